// Round 7
// baseline (396.889 us; speedup 1.0000x reference)
//
#include <hip/hip_runtime.h>

// ---------- types / helpers ----------
typedef __attribute__((ext_vector_type(8))) short bf16x8;
typedef __attribute__((ext_vector_type(4))) float f32x4;

#define DEVFN static __device__ __forceinline__

DEVFN float bf2f(unsigned short u) {
    union { unsigned u; float f; } x; x.u = ((unsigned)u) << 16; return x.f;
}
DEVFN unsigned short f2bf(float f) {
    union { float f; unsigned u; } x; x.f = f;
    unsigned r = x.u + 0x7fffu + ((x.u >> 16) & 1u);   // RNE
    return (unsigned short)(r >> 16);
}
// raw-rate transcendentals (bf16-grade precision is plenty)
DEVFN float exp2_raw(float x) { float r; asm("v_exp_f32 %0, %1" : "=v"(r) : "v"(x)); return r; }
DEVFN float rcp_raw(float x)  { float r; asm("v_rcp_f32 %0, %1" : "=v"(r) : "v"(x)); return r; }
DEVFN unsigned cvt_pk_bf16(float lo, float hi) {
    unsigned r; asm("v_cvt_pk_bf16_f32 %0, %1, %2" : "=v"(r) : "v"(lo), "v"(hi)); return r;
}

#define GCAST(p) ((const __attribute__((address_space(1))) void*)(p))
#define LCAST(p) ((__attribute__((address_space(3))) void*)(p))

// Problem dims
// B=512 N=64 E=128 AF=39 BF=89 LF=18 EF=5 H=128
// X     : [64*512][192] bf16  (rows m = n*512+b; [fa|fb|fl|0pad])
// tree  : [64][512][896]  bf16 (time-major rows m = n*512+b)
// gi    : [d][bs(32)][t(64)][j(384)][bb(16)] bf16   (b = bs*16+bb) -- scan-streaming layout
// h1/h2 : [64][512][256]  bf16 (rows m = t*512+b)

// ---------- fused weight prep ----------
__global__ void k_prepw(const float* __restrict__ wih0f, const float* __restrict__ wih1f,
                        const float* __restrict__ whh0f, const float* __restrict__ whh1f,
                        const float* __restrict__ attw,
                        const float* __restrict__ aw, const float* __restrict__ bw, const float* __restrict__ lw,
                        const float* __restrict__ bih0, const float* __restrict__ bhh0,
                        const float* __restrict__ bih1, const float* __restrict__ bhh1,
                        unsigned short* __restrict__ wih0, unsigned short* __restrict__ wih1,
                        unsigned short* __restrict__ whh0, unsigned short* __restrict__ whh1,
                        unsigned short* __restrict__ awT, unsigned short* __restrict__ wcat,
                        float* __restrict__ cb0, float* __restrict__ cb1)
{
    int i = blockIdx.x * 256 + threadIdx.x;
    if (i < 688128) { wih0[i] = f2bf(wih0f[i]); return; }
    i -= 688128;
    if (i < 196608) { wih1[i] = f2bf(wih1f[i]); return; }
    i -= 196608;
    if (i < 98304) { whh0[i] = f2bf(whh0f[i]); return; }
    i -= 98304;
    if (i < 98304) { whh1[i] = f2bf(whh1f[i]); return; }
    i -= 98304;
    if (i < 65536) { int nn = i >> 8, k = i & 255; awT[nn * 256 + k] = f2bf(attw[k * 256 + nn]); return; }
    i -= 65536;
    if (i < 73728) {
        int n = i / 192, k = i - n * 192;
        float v = 0.f;
        if (n < 128)      { if (k < 39)             v = aw[k * 128 + n]; }
        else if (n < 256) { if (k >= 39 && k < 128) v = bw[(k - 39) * 128 + (n - 128)]; }
        else              { if (k >= 128 && k < 146) v = lw[(k - 128) * 128 + (n - 256)]; }
        wcat[n * 192 + k] = f2bf(v);
        return;
    }
    i -= 73728;
    // combined GEMM bias: bih + bhh for r,z gates (j%384 < 256); bih only for n gate
    if (i < 768) { int jj = i % 384; cb0[i] = bih0[i] + (jj < 256 ? bhh0[i] : 0.f); return; }
    i -= 768;
    if (i < 768) { int jj = i % 384; cb1[i] = bih1[i] + (jj < 256 ? bhh1[i] : 0.f); return; }
}

// ---------- pack inputs into X [32768][192] bf16 ----------
__global__ __launch_bounds__(256) void k_pack(
    const float* __restrict__ fa, const float* __restrict__ fb, const float* __restrict__ fl,
    unsigned short* __restrict__ X)
{
    const int b = blockIdx.x, tid = threadIdx.x;
    for (int idx = tid; idx < 64 * 192; idx += 256) {
        int n = idx / 192, k = idx - n * 192;
        float v = 0.f;
        if (k < 39)       v = fa[(size_t)(b * 64 + n) * 39 + k];
        else if (k < 128) v = fb[(size_t)(b * 64 + n) * 89 + (k - 39)];
        else if (k < 146) v = fl[(size_t)(b * 64 + n) * 18 + (k - 128)];
        X[((size_t)(n * 512 + b)) * 192 + k] = f2bf(v);
    }
}

// ---------- nodevec GEMM: tree[:, 0:384] = relu(X @ Wcat^T + bias) ----------
// 1D grid, XCD-swizzled, nt fast: lin = mt*3 + nt
__global__ __launch_bounds__(256, 4) void k_nv(
    const unsigned short* __restrict__ X,
    const unsigned short* __restrict__ Wc,
    const float* __restrict__ ab, const float* __restrict__ bb_, const float* __restrict__ lb,
    unsigned short* __restrict__ tree)
{
    __shared__ unsigned short As[128 * 64];
    __shared__ unsigned short Bs[128 * 64];
    const int bid = blockIdx.x;                    // 768 = 8 * 96
    const int lin = (bid & 7) * 96 + (bid >> 3);
    const int mt = lin / 3, nt = lin - mt * 3;
    const int tid = threadIdx.x, wave = tid >> 6, lane = tid & 63;
    const int m0 = mt << 7, n0 = nt << 7;
    f32x4 acc[4][4] = {};

    for (int k0 = 0; k0 < 192; k0 += 64) {
        __syncthreads();
        #pragma unroll
        for (int i = 0; i < 4; ++i) {
            int ins = wave * 4 + i;
            int r = ins * 8 + (lane >> 3);
            int c = (lane & 7) * 8;
            const unsigned short* sa = X + (size_t)(m0 + r) * 192 + k0 + c;
            const unsigned short* sb = Wc + (size_t)(n0 + r) * 192 + k0 + c;
            __builtin_amdgcn_global_load_lds(GCAST(sa), LCAST(As + ins * 512), 16, 0, 0);
            __builtin_amdgcn_global_load_lds(GCAST(sb), LCAST(Bs + ins * 512), 16, 0, 0);
        }
        __syncthreads();
        #pragma unroll
        for (int ks = 0; ks < 2; ++ks) {
            bf16x8 af[4], bfr[4];
            int kk = ks * 32 + ((lane >> 4) << 3);
            #pragma unroll
            for (int mi = 0; mi < 4; ++mi)
                af[mi] = *(const bf16x8*)(As + (((wave & 1) << 6) + mi * 16 + (lane & 15)) * 64 + kk);
            #pragma unroll
            for (int ni = 0; ni < 4; ++ni)
                bfr[ni] = *(const bf16x8*)(Bs + (((wave >> 1) << 6) + ni * 16 + (lane & 15)) * 64 + kk);
            #pragma unroll
            for (int mi = 0; mi < 4; ++mi)
                #pragma unroll
                for (int ni = 0; ni < 4; ++ni)
                    acc[mi][ni] = __builtin_amdgcn_mfma_f32_16x16x32_bf16(af[mi], bfr[ni], acc[mi][ni], 0, 0, 0);
        }
    }

    const float* bias_arr = (n0 == 0) ? ab : (n0 == 128) ? bb_ : lb;
    #pragma unroll
    for (int ni = 0; ni < 4; ++ni) {
        int cl = ((wave >> 1) << 6) + ni * 16 + (lane & 15);
        float bias = bias_arr[cl];
        int cg = n0 + cl;
        #pragma unroll
        for (int mi = 0; mi < 4; ++mi) {
            int r0 = m0 + ((wave & 1) << 6) + mi * 16 + ((lane >> 4) << 2);
            #pragma unroll
            for (int reg = 0; reg < 4; ++reg) {
                float v = fmaxf(acc[mi][ni][reg] + bias, 0.f);
                tree[(size_t)(r0 + reg) * 896 + cg] = f2bf(v);
            }
        }
    }
}

// ---------- segment-sum aggregation: tree[:, 384:896] ----------
__global__ __launch_bounds__(256, 2) void k_agg(
    unsigned short* __restrict__ tree,
    const float* __restrict__ efi, const int* __restrict__ esrc, const int* __restrict__ edst,
    const float* __restrict__ ew, const float* __restrict__ eb)
{
    const int b = blockIdx.x, tid = threadIdx.x;
    __shared__ float agg[64 * 256];   // 64 KB

    float ewr[5], ebr = 0.f;
    if (tid >= 128) {
        int ce = tid - 128;
        #pragma unroll
        for (int i = 0; i < 5; ++i) ewr[i] = ew[i * 128 + ce];
        ebr = eb[ce];
    }
    const int* se = esrc + b * 128;
    const int* de = edst + b * 128;
    const float* ef = efi + (size_t)b * 640;

    for (int pass = 0; pass < 2; ++pass) {
        __syncthreads();
        for (int i = tid; i < 16384; i += 256) agg[i] = 0.f;
        __syncthreads();
        const int cg = pass * 256 + tid;
        if (pass == 0 || tid < 128) {
            #pragma unroll 4
            for (int e = 0; e < 128; ++e) {
                float v = bf2f(tree[((size_t)(de[e] * 512 + b)) * 896 + cg]);
                agg[se[e] * 256 + tid] += v;
            }
        } else {
            #pragma unroll 4
            for (int e = 0; e < 128; ++e) {
                const float* x = ef + e * 5;
                float s = ebr;
                #pragma unroll
                for (int i = 0; i < 5; ++i) s += x[i] * ewr[i];
                agg[se[e] * 256 + tid] += fmaxf(s, 0.f);
            }
        }
        __syncthreads();
        for (int i = tid; i < 16384; i += 256) {
            int n = i >> 8, c = i & 255;
            tree[((size_t)(n * 512 + b)) * 896 + 384 + pass * 256 + c] = f2bf(agg[i]);
        }
    }
}

// ---------- GEMM: gi[d][bs][t][j][bb] = A @ W^T + cbias ----------
// A: [32768][K] bf16 (m = t*512 + b), W: [768][K] bf16
// 1D grid NT*256 blocks, XCD-swizzled, nt fast: lin = mt*NT + nt
template<int NT>
__global__ __launch_bounds__(256, 4) void k_gemm(
    const unsigned short* __restrict__ A,
    const unsigned short* __restrict__ W,
    const float* __restrict__ cb,
    unsigned short* __restrict__ gi,
    int K)
{
    __shared__ unsigned short As[128 * 64];
    __shared__ unsigned short Bs[128 * 64];
    const int nblk = NT * 256;
    const int cpx = nblk >> 3;
    const int bid = blockIdx.x;
    const int lin = (bid & 7) * cpx + (bid >> 3);
    const int mt = lin / NT, nt = lin - mt * NT;
    const int tid = threadIdx.x, wave = tid >> 6, lane = tid & 63;
    const int m0 = mt << 7, n0 = nt << 7;
    f32x4 acc[4][4] = {};

    for (int k0 = 0; k0 < K; k0 += 64) {
        __syncthreads();
        #pragma unroll
        for (int i = 0; i < 4; ++i) {
            int ins = wave * 4 + i;
            int r = ins * 8 + (lane >> 3);
            int c = (lane & 7) * 8;
            const unsigned short* sa = A + (size_t)(m0 + r) * K + k0 + c;
            const unsigned short* sb = W + (size_t)(n0 + r) * K + k0 + c;
            __builtin_amdgcn_global_load_lds(GCAST(sa), LCAST(As + ins * 512), 16, 0, 0);
            __builtin_amdgcn_global_load_lds(GCAST(sb), LCAST(Bs + ins * 512), 16, 0, 0);
        }
        __syncthreads();
        #pragma unroll
        for (int ks = 0; ks < 2; ++ks) {
            bf16x8 af[4], bfr[4];
            int kk = ks * 32 + ((lane >> 4) << 3);
            #pragma unroll
            for (int mi = 0; mi < 4; ++mi)
                af[mi] = *(const bf16x8*)(As + (((wave & 1) << 6) + mi * 16 + (lane & 15)) * 64 + kk);
            #pragma unroll
            for (int ni = 0; ni < 4; ++ni)
                bfr[ni] = *(const bf16x8*)(Bs + (((wave >> 1) << 6) + ni * 16 + (lane & 15)) * 64 + kk);
            #pragma unroll
            for (int mi = 0; mi < 4; ++mi)
                #pragma unroll
                for (int ni = 0; ni < 4; ++ni)
                    acc[mi][ni] = __builtin_amdgcn_mfma_f32_16x16x32_bf16(af[mi], bfr[ni], acc[mi][ni], 0, 0, 0);
        }
    }

    // epilogue: rows in this tile share one t; write scan-streaming layout
    const int tseq = m0 >> 9;
    const int d = n0 / 384;
    const int j0 = n0 - d * 384;
    const int bglob = (m0 & 511) + ((wave & 1) << 6) + ((lane >> 4) << 2);
    #pragma unroll
    for (int ni = 0; ni < 4; ++ni) {
        int j = j0 + ((wave >> 1) << 6) + ni * 16 + (lane & 15);
        float bias = cb[d * 384 + j];
        #pragma unroll
        for (int mi = 0; mi < 4; ++mi) {
            int b = bglob + mi * 16;
            int bs = b >> 4, bb = b & 15;
            ushort4 v;
            v.x = f2bf(acc[mi][ni][0] + bias);
            v.y = f2bf(acc[mi][ni][1] + bias);
            v.z = f2bf(acc[mi][ni][2] + bias);
            v.w = f2bf(acc[mi][ni][3] + bias);
            *(ushort4*)(gi + (((size_t)(d * 32 + bs) * 64 + tseq) * 384 + j) * 16 + bb) = v;
        }
    }
}

// ---------- GRU scan: 512 threads, 8 waves; wave w owns hidden cols [w*16,(w+1)*16) ----------
__global__ __launch_bounds__(512, 1) void k_scan(
    const unsigned short* __restrict__ gi,   // [d][bs][t][j][bb]  (r,z parts pre-biased with bhh)
    const unsigned short* __restrict__ whh,  // [2][384][128] bf16
    const float* __restrict__ bhh,           // [2][384] (only n-gate part used)
    unsigned short* __restrict__ hout)       // [64][512][256]
{
    const int d = blockIdx.y, bs = blockIdx.x;
    const int b0 = bs << 4;
    const int tid = threadIdx.x, wave = tid >> 6, lane = tid & 63;
    __shared__ unsigned short hs[2][2048];   // 2 x (16 rows x 128 cols), XOR-swizzled
    for (int i = tid; i < 2048; i += 512) hs[0][i] = 0;

    const int colh = (wave << 4) + (lane & 15);
    // whh fragments: 3 gates x K=128 (4 slices)
    bf16x8 wf[3][4];
    #pragma unroll
    for (int g = 0; g < 3; ++g) {
        int j = g * 128 + colh;
        #pragma unroll
        for (int ks = 0; ks < 4; ++ks)
            wf[g][ks] = *(const bf16x8*)(whh + ((d * 384 + j) << 7) + ks * 32 + ((lane >> 4) << 3));
    }
    const float bh2 = bhh[d * 384 + 256 + colh];
    const float L2E = 1.4426950408889634f;

    int joff[3];
    #pragma unroll
    for (int g = 0; g < 3; ++g)
        joff[g] = (g * 128 + colh) * 16 + ((lane >> 4) << 2);

    // hoisted addressing: XOR mask applied AFTER the ks*64 add (mask bit6 overlaps ks*64!)
    const int arow = lane & 15;
    const int amask = (arow & 7) << 4;
    const int abase = (arow << 8) + (((lane >> 4) << 3) << 1);
    // gate LDS writes: rows r0..r0+3 at col colh (XOR-only, safe to hoist fully)
    const int r0 = (lane >> 4) << 2;
    const int c2 = colh << 1;
    const int wb0 = (((r0 + 0) << 8) + c2) ^ (((r0 + 0) & 7) << 4);
    const int wb1 = (((r0 + 1) << 8) + c2) ^ (((r0 + 1) & 7) << 4);
    const int wb2 = (((r0 + 2) << 8) + c2) ^ (((r0 + 2) & 7) << 4);
    const int wb3 = (((r0 + 3) << 8) + c2) ^ (((r0 + 3) & 7) << 4);

    // cooperative-store mapping: thread -> (srow, scol) of the 16x128 h tile
    const int srow = tid >> 5;
    const int scol = (tid & 31) << 2;
    const int sbyte = ((srow << 8) + (scol << 1)) ^ ((srow & 7) << 4);
    const int t0 = d ? 63 : 0;
    unsigned short* sp = hout + ((size_t)(t0 * 512 + b0 + srow)) * 256 + d * 128 + scol;
    const ptrdiff_t sdelta = d ? -(ptrdiff_t)131072 : (ptrdiff_t)131072;

    // streaming gi pointer, advanced by +-6144 elems per step
    const unsigned short* gp = gi + (size_t)(d * 32 + bs) * 64 * 6144 + (size_t)t0 * 6144;
    const ptrdiff_t gdelta = d ? -(ptrdiff_t)6144 : (ptrdiff_t)6144;

    float hold[4] = {};
    uint2 cur[3], nxt[3];
    #pragma unroll
    for (int g = 0; g < 3; ++g)
        cur[g] = *(const uint2*)(gp + joff[g]);
    gp += gdelta;

    asm volatile("s_waitcnt lgkmcnt(0)" ::: "memory");
    __builtin_amdgcn_s_barrier();
    __builtin_amdgcn_sched_barrier(0);

    for (int s = 0; s < 64; ++s) {
        // prefetch next step's gi (safe overread on last step; never consumed)
        #pragma unroll
        for (int g = 0; g < 3; ++g)
            nxt[g] = *(const uint2*)(gp + joff[g]);
        gp += gdelta;

        const unsigned short* hsrc = hs[s & 1];

        // cooperative store of h_{s-1} (lives in hsrc), overlapped with MFMA
        uint2 hv;
        if (s > 0) hv = *(const uint2*)((const char*)hsrc + sbyte);

        // gh = h @ whh.T for this wave's 16 cols x 3 gates
        f32x4 acc[3] = {};
        #pragma unroll
        for (int ks = 0; ks < 4; ++ks) {
            bf16x8 a = *(const bf16x8*)((const char*)hsrc + ((abase + ks * 64) ^ amask));
            #pragma unroll
            for (int g = 0; g < 3; ++g)
                acc[g] = __builtin_amdgcn_mfma_f32_16x16x32_bf16(a, wf[g][ks], acc[g], 0, 0, 0);
        }

        if (s > 0) { *(uint2*)sp = hv; sp += sdelta; }

        // gates: 4 batch rows (regs) x 1 col per thread; lean VALU forms
        unsigned short* hdst = hs[(s & 1) ^ 1];
        const ushort4 cr = *(const ushort4*)&cur[0];
        const ushort4 cz = *(const ushort4*)&cur[1];
        const ushort4 cn = *(const ushort4*)&cur[2];
        float hn[4];
        #pragma unroll
        for (int reg = 0; reg < 4; ++reg) {
            float r = rcp_raw(1.f + exp2_raw((bf2f((&cr.x)[reg]) + acc[0][reg]) * -L2E));
            float z = rcp_raw(1.f + exp2_raw((bf2f((&cz.x)[reg]) + acc[1][reg]) * -L2E));
            float gn = bf2f((&cn.x)[reg]) + r * (acc[2][reg] + bh2);
            float n = 1.f - 2.f * rcp_raw(1.f + exp2_raw(gn * (2.f * L2E)));
            hn[reg] = n + z * (hold[reg] - n);
            hold[reg] = hn[reg];
        }
        {
            unsigned p01 = cvt_pk_bf16(hn[0], hn[1]);
            unsigned p23 = cvt_pk_bf16(hn[2], hn[3]);
            *(unsigned short*)((char*)hdst + wb0) = (unsigned short)p01;
            *(unsigned short*)((char*)hdst + wb1) = (unsigned short)(p01 >> 16);
            *(unsigned short*)((char*)hdst + wb2) = (unsigned short)p23;
            *(unsigned short*)((char*)hdst + wb3) = (unsigned short)(p23 >> 16);
        }
        asm volatile("s_waitcnt lgkmcnt(0)" ::: "memory");
        __builtin_amdgcn_s_barrier();
        __builtin_amdgcn_sched_barrier(0);
        #pragma unroll
        for (int g = 0; g < 3; ++g)
            cur[g] = nxt[g];
    }
    // final h_63 lives in hs[0]
    uint2 hv = *(const uint2*)((const char*)hs[0] + sbyte);
    *(uint2*)sp = hv;
}

// ---------- attention ----------
__global__ __launch_bounds__(256, 2) void k_attn(
    const unsigned short* __restrict__ h2,   // [64][512][256]
    const unsigned short* __restrict__ awT,  // [256][256] transposed att_w
    const float* __restrict__ att_b, const float* __restrict__ a_w, const float* __restrict__ a_b,
    float* __restrict__ out)                 // [512][256]
{
    const int b = blockIdx.x, tid = threadIdx.x, wave = tid >> 6, lane = tid & 63;
    __shared__ unsigned short vw[64 * 264];
    __shared__ float red[256];
    __shared__ float sc[64];
    __shared__ float scal[2];

    for (int i = tid; i < 2048; i += 256) {
        int t = i >> 5; int c = (i & 31) << 3;
        bf16x8 v = *(const bf16x8*)(h2 + ((size_t)t * 512 + b) * 256 + c);
        int byte = (t << 9) + (c << 1); byte ^= (t & 7) << 4;
        *(bf16x8*)((char*)vw + byte) = v;
    }
    __syncthreads();

    f32x4 acc[4][4] = {};
    const int colbase = wave << 6;
    #pragma unroll
    for (int ks = 0; ks < 8; ++ks) {
        bf16x8 a[4], bf[4];
        int kk = ks * 32 + ((lane >> 4) << 3);
        #pragma unroll
        for (int mt = 0; mt < 4; ++mt) {
            int row = mt * 16 + (lane & 15);
            int byte = (row << 9) + (kk << 1); byte ^= (row & 7) << 4;
            a[mt] = *(const bf16x8*)((const char*)vw + byte);
        }
        #pragma unroll
        for (int nt = 0; nt < 4; ++nt) {
            int cg = colbase + nt * 16 + (lane & 15);
            bf[nt] = *(const bf16x8*)(awT + cg * 256 + kk);
        }
        #pragma unroll
        for (int mt = 0; mt < 4; ++mt)
            #pragma unroll
            for (int nt = 0; nt < 4; ++nt)
                acc[mt][nt] = __builtin_amdgcn_mfma_f32_16x16x32_bf16(a[mt], bf[nt], acc[mt][nt], 0, 0, 0);
    }
    __syncthreads();

    #pragma unroll
    for (int mt = 0; mt < 4; ++mt)
        #pragma unroll
        for (int nt = 0; nt < 4; ++nt) {
            int cg = colbase + nt * 16 + (lane & 15);
            float bias = att_b[cg];
            int r0 = mt * 16 + ((lane >> 4) << 2);
            #pragma unroll
            for (int reg = 0; reg < 4; ++reg)
                vw[(r0 + reg) * 264 + cg] = f2bf(acc[mt][nt][reg] + bias);
        }
    __syncthreads();

    float wsum = 0.f;
    for (int t = 0; t < 64; ++t) wsum += bf2f(vw[t * 264 + tid]);
    float p = (wsum * (1.f / 64.f)) * a_w[tid];
    #pragma unroll
    for (int off = 32; off; off >>= 1) p += __shfl_down(p, off, 64);
    if (lane == 0) red[wave] = p;
    __syncthreads();
    float s0 = red[0] + red[1] + red[2] + red[3];
    __syncthreads();

    {
        int t4 = tid >> 2, part = tid & 3;
        float ps = 0.f;
        for (int c = part * 64; c < part * 64 + 64; ++c)
            ps += bf2f(vw[t4 * 264 + c]) * a_w[256 + c];
        red[tid] = ps;
    }
    __syncthreads();
    if (tid < 64) {
        float s = red[tid * 4] + red[tid * 4 + 1] + red[tid * 4 + 2] + red[tid * 4 + 3] + s0 + a_b[0];
        s = (s > 0.f) ? s : 0.01f * s;
        sc[tid] = __expf(s);
    }
    __syncthreads();
    if (tid < 64) {
        float e = sc[tid];
        #pragma unroll
        for (int off = 32; off; off >>= 1) e += __shfl_down(e, off, 64);
        if (tid == 0) scal[0] = e;
    }
    __syncthreads();
    const float inv_den = 1.f / scal[0];

    float o = 0.f;
    for (int t = 0; t < 64; ++t) o += sc[t] * bf2f(vw[t * 264 + tid]);
    out[b * 256 + tid] = fmaxf(o * inv_den, 0.f);
}

// ---------- launch ----------
extern "C" void kernel_launch(void* const* d_in, const int* in_sizes, int n_in,
                              void* d_out, int out_size, void* d_ws, size_t ws_size,
                              hipStream_t stream) {
    (void)in_sizes; (void)n_in; (void)out_size; (void)ws_size;
    const float* fa  = (const float*)d_in[0];
    const float* fb  = (const float*)d_in[1];
    const float* fl  = (const float*)d_in[2];
    const float* efi = (const float*)d_in[3];
    const int* esrc  = (const int*)d_in[4];
    const int* edst  = (const int*)d_in[5];

    char* ws = (char*)d_ws;
    unsigned short* tree = (unsigned short*)(ws);                    // 58,720,256 B
    unsigned short* h1   = (unsigned short*)(ws);                    // aliases tree (dead by then)
    unsigned short* h2   = (unsigned short*)(ws + 16777216);
    unsigned short* gi   = (unsigned short*)(ws + 58720256);         // 50,331,648 B
    unsigned short* X    = (unsigned short*)(ws + 58720256);         // aliases gi (dead before gemm0)
    unsigned short* wih0 = (unsigned short*)(ws + 109051904);
    unsigned short* wih1 = (unsigned short*)(ws + 110428160);
    unsigned short* whh0 = (unsigned short*)(ws + 110821376);
    unsigned short* whh1 = (unsigned short*)(ws + 111017984);
    unsigned short* awT  = (unsigned short*)(ws + 111214592);
    unsigned short* wcat = (unsigned short*)(ws + 111345664);        // 147,456 B
    float* cb0 = (float*)(ws + 111493120);                           // 3072 B
    float* cb1 = (float*)(ws + 111496192);                           // 3072 B

    k_prepw<<<4775, 256, 0, stream>>>(
        (const float*)d_in[14], (const float*)d_in[18], (const float*)d_in[15], (const float*)d_in[19],
        (const float*)d_in[22], (const float*)d_in[6], (const float*)d_in[8], (const float*)d_in[10],
        (const float*)d_in[16], (const float*)d_in[17], (const float*)d_in[20], (const float*)d_in[21],
        wih0, wih1, whh0, whh1, awT, wcat, cb0, cb1);

    k_pack<<<512, 256, 0, stream>>>(fa, fb, fl, X);
    k_nv<<<768, 256, 0, stream>>>(X, wcat,
        (const float*)d_in[7], (const float*)d_in[9], (const float*)d_in[11], tree);
    k_agg<<<512, 256, 0, stream>>>(tree, efi, esrc, edst,
        (const float*)d_in[12], (const float*)d_in[13]);

    k_gemm<6><<<1536, 256, 0, stream>>>(tree, wih0, cb0, gi, 896);
    k_scan<<<dim3(32, 2), 512, 0, stream>>>(gi, whh0, (const float*)d_in[17], h1);
    k_gemm<6><<<1536, 256, 0, stream>>>(h1, wih1, cb1, gi, 256);
    k_scan<<<dim3(32, 2), 512, 0, stream>>>(gi, whh1, (const float*)d_in[21], h2);
    k_attn<<<512, 256, 0, stream>>>(h2, awT, (const float*)d_in[23], (const float*)d_in[24],
                                    (const float*)d_in[25], (float*)d_out);
}

// Round 8
// 381.703 us; speedup vs baseline: 1.0398x; 1.0398x over previous
//
#include <hip/hip_runtime.h>

// ---------- types / helpers ----------
typedef __attribute__((ext_vector_type(8))) short bf16x8;
typedef __attribute__((ext_vector_type(4))) float f32x4;

#define DEVFN static __device__ __forceinline__

DEVFN float bf2f(unsigned short u) {
    union { unsigned u; float f; } x; x.u = ((unsigned)u) << 16; return x.f;
}
DEVFN unsigned short f2bf(float f) {
    union { float f; unsigned u; } x; x.f = f;
    unsigned r = x.u + 0x7fffu + ((x.u >> 16) & 1u);   // RNE
    return (unsigned short)(r >> 16);
}
// raw-rate transcendentals (bf16-grade precision is plenty)
DEVFN float exp2_raw(float x) { float r; asm("v_exp_f32 %0, %1" : "=v"(r) : "v"(x)); return r; }
DEVFN float rcp_raw(float x)  { float r; asm("v_rcp_f32 %0, %1" : "=v"(r) : "v"(x)); return r; }
DEVFN unsigned cvt_pk_bf16(float lo, float hi) {
    unsigned r; asm("v_cvt_pk_bf16_f32 %0, %1, %2" : "=v"(r) : "v"(lo), "v"(hi)); return r;
}

#define GCAST(p) ((const __attribute__((address_space(1))) void*)(p))
#define LCAST(p) ((__attribute__((address_space(3))) void*)(p))

// Problem dims
// B=512 N=64 E=128 AF=39 BF=89 LF=18 EF=5 H=128
// X     : [64*512][192] bf16  (rows m = n*512+b; [fa|fb|fl|0pad])
// tree  : [64][512][896]  bf16 (time-major rows m = n*512+b)
// gi    : [d][bs(32)][t(64)][j(384)][bb(16)] bf16   (b = bs*16+bb) -- scan-streaming layout
// h1/h2 : [64][512][256]  bf16 (rows m = t*512+b)

// ---------- fused weight prep ----------
__global__ void k_prepw(const float* __restrict__ wih0f, const float* __restrict__ wih1f,
                        const float* __restrict__ whh0f, const float* __restrict__ whh1f,
                        const float* __restrict__ attw,
                        const float* __restrict__ aw, const float* __restrict__ bw, const float* __restrict__ lw,
                        const float* __restrict__ bih0, const float* __restrict__ bhh0,
                        const float* __restrict__ bih1, const float* __restrict__ bhh1,
                        unsigned short* __restrict__ wih0, unsigned short* __restrict__ wih1,
                        unsigned short* __restrict__ whh0, unsigned short* __restrict__ whh1,
                        unsigned short* __restrict__ awT, unsigned short* __restrict__ wcat,
                        float* __restrict__ cb0, float* __restrict__ cb1)
{
    int i = blockIdx.x * 256 + threadIdx.x;
    if (i < 688128) { wih0[i] = f2bf(wih0f[i]); return; }
    i -= 688128;
    if (i < 196608) { wih1[i] = f2bf(wih1f[i]); return; }
    i -= 196608;
    if (i < 98304) { whh0[i] = f2bf(whh0f[i]); return; }
    i -= 98304;
    if (i < 98304) { whh1[i] = f2bf(whh1f[i]); return; }
    i -= 98304;
    if (i < 65536) { int nn = i >> 8, k = i & 255; awT[nn * 256 + k] = f2bf(attw[k * 256 + nn]); return; }
    i -= 65536;
    if (i < 73728) {
        int n = i / 192, k = i - n * 192;
        float v = 0.f;
        if (n < 128)      { if (k < 39)             v = aw[k * 128 + n]; }
        else if (n < 256) { if (k >= 39 && k < 128) v = bw[(k - 39) * 128 + (n - 128)]; }
        else              { if (k >= 128 && k < 146) v = lw[(k - 128) * 128 + (n - 256)]; }
        wcat[n * 192 + k] = f2bf(v);
        return;
    }
    i -= 73728;
    // combined GEMM bias: bih + bhh for r,z gates (j%384 < 256); bih only for n gate
    if (i < 768) { int jj = i % 384; cb0[i] = bih0[i] + (jj < 256 ? bhh0[i] : 0.f); return; }
    i -= 768;
    if (i < 768) { int jj = i % 384; cb1[i] = bih1[i] + (jj < 256 ? bhh1[i] : 0.f); return; }
}

// ---------- pack inputs into X [32768][192] bf16 ----------
__global__ __launch_bounds__(256) void k_pack(
    const float* __restrict__ fa, const float* __restrict__ fb, const float* __restrict__ fl,
    unsigned short* __restrict__ X)
{
    const int b = blockIdx.x, tid = threadIdx.x;
    for (int idx = tid; idx < 64 * 192; idx += 256) {
        int n = idx / 192, k = idx - n * 192;
        float v = 0.f;
        if (k < 39)       v = fa[(size_t)(b * 64 + n) * 39 + k];
        else if (k < 128) v = fb[(size_t)(b * 64 + n) * 89 + (k - 39)];
        else if (k < 146) v = fl[(size_t)(b * 64 + n) * 18 + (k - 128)];
        X[((size_t)(n * 512 + b)) * 192 + k] = f2bf(v);
    }
}

// ---------- nodevec GEMM: tree[:, 0:384] = relu(X @ Wcat^T + bias) ----------
// 1D grid, XCD-swizzled, nt fast: lin = mt*3 + nt
__global__ __launch_bounds__(256, 4) void k_nv(
    const unsigned short* __restrict__ X,
    const unsigned short* __restrict__ Wc,
    const float* __restrict__ ab, const float* __restrict__ bb_, const float* __restrict__ lb,
    unsigned short* __restrict__ tree)
{
    __shared__ unsigned short As[128 * 64];
    __shared__ unsigned short Bs[128 * 64];
    const int bid = blockIdx.x;                    // 768 = 8 * 96
    const int lin = (bid & 7) * 96 + (bid >> 3);
    const int mt = lin / 3, nt = lin - mt * 3;
    const int tid = threadIdx.x, wave = tid >> 6, lane = tid & 63;
    const int m0 = mt << 7, n0 = nt << 7;
    f32x4 acc[4][4] = {};

    for (int k0 = 0; k0 < 192; k0 += 64) {
        __syncthreads();
        #pragma unroll
        for (int i = 0; i < 4; ++i) {
            int ins = wave * 4 + i;
            int r = ins * 8 + (lane >> 3);
            int c = (lane & 7) * 8;
            const unsigned short* sa = X + (size_t)(m0 + r) * 192 + k0 + c;
            const unsigned short* sb = Wc + (size_t)(n0 + r) * 192 + k0 + c;
            __builtin_amdgcn_global_load_lds(GCAST(sa), LCAST(As + ins * 512), 16, 0, 0);
            __builtin_amdgcn_global_load_lds(GCAST(sb), LCAST(Bs + ins * 512), 16, 0, 0);
        }
        __syncthreads();
        #pragma unroll
        for (int ks = 0; ks < 2; ++ks) {
            bf16x8 af[4], bfr[4];
            int kk = ks * 32 + ((lane >> 4) << 3);
            #pragma unroll
            for (int mi = 0; mi < 4; ++mi)
                af[mi] = *(const bf16x8*)(As + (((wave & 1) << 6) + mi * 16 + (lane & 15)) * 64 + kk);
            #pragma unroll
            for (int ni = 0; ni < 4; ++ni)
                bfr[ni] = *(const bf16x8*)(Bs + (((wave >> 1) << 6) + ni * 16 + (lane & 15)) * 64 + kk);
            #pragma unroll
            for (int mi = 0; mi < 4; ++mi)
                #pragma unroll
                for (int ni = 0; ni < 4; ++ni)
                    acc[mi][ni] = __builtin_amdgcn_mfma_f32_16x16x32_bf16(af[mi], bfr[ni], acc[mi][ni], 0, 0, 0);
        }
    }

    const float* bias_arr = (n0 == 0) ? ab : (n0 == 128) ? bb_ : lb;
    #pragma unroll
    for (int ni = 0; ni < 4; ++ni) {
        int cl = ((wave >> 1) << 6) + ni * 16 + (lane & 15);
        float bias = bias_arr[cl];
        int cg = n0 + cl;
        #pragma unroll
        for (int mi = 0; mi < 4; ++mi) {
            int r0 = m0 + ((wave & 1) << 6) + mi * 16 + ((lane >> 4) << 2);
            #pragma unroll
            for (int reg = 0; reg < 4; ++reg) {
                float v = fmaxf(acc[mi][ni][reg] + bias, 0.f);
                tree[(size_t)(r0 + reg) * 896 + cg] = f2bf(v);
            }
        }
    }
}

// ---------- segment-sum aggregation: tree[:, 384:896] ----------
__global__ __launch_bounds__(256, 2) void k_agg(
    unsigned short* __restrict__ tree,
    const float* __restrict__ efi, const int* __restrict__ esrc, const int* __restrict__ edst,
    const float* __restrict__ ew, const float* __restrict__ eb)
{
    const int b = blockIdx.x, tid = threadIdx.x;
    __shared__ float agg[64 * 256];   // 64 KB

    float ewr[5], ebr = 0.f;
    if (tid >= 128) {
        int ce = tid - 128;
        #pragma unroll
        for (int i = 0; i < 5; ++i) ewr[i] = ew[i * 128 + ce];
        ebr = eb[ce];
    }
    const int* se = esrc + b * 128;
    const int* de = edst + b * 128;
    const float* ef = efi + (size_t)b * 640;

    for (int pass = 0; pass < 2; ++pass) {
        __syncthreads();
        for (int i = tid; i < 16384; i += 256) agg[i] = 0.f;
        __syncthreads();
        const int cg = pass * 256 + tid;
        if (pass == 0 || tid < 128) {
            #pragma unroll 4
            for (int e = 0; e < 128; ++e) {
                float v = bf2f(tree[((size_t)(de[e] * 512 + b)) * 896 + cg]);
                agg[se[e] * 256 + tid] += v;
            }
        } else {
            #pragma unroll 4
            for (int e = 0; e < 128; ++e) {
                const float* x = ef + e * 5;
                float s = ebr;
                #pragma unroll
                for (int i = 0; i < 5; ++i) s += x[i] * ewr[i];
                agg[se[e] * 256 + tid] += fmaxf(s, 0.f);
            }
        }
        __syncthreads();
        for (int i = tid; i < 16384; i += 256) {
            int n = i >> 8, c = i & 255;
            tree[((size_t)(n * 512 + b)) * 896 + 384 + pass * 256 + c] = f2bf(agg[i]);
        }
    }
}

// ---------- GEMM: gi[d][bs][t][j][bb] = A @ W^T + cbias ----------
// A: [32768][K] bf16 (m = t*512 + b), W: [768][K] bf16
// 1D grid NT*256 blocks, XCD-swizzled, nt fast: lin = mt*NT + nt
template<int NT>
__global__ __launch_bounds__(256, 4) void k_gemm(
    const unsigned short* __restrict__ A,
    const unsigned short* __restrict__ W,
    const float* __restrict__ cb,
    unsigned short* __restrict__ gi,
    int K)
{
    __shared__ unsigned short As[128 * 64];
    __shared__ unsigned short Bs[128 * 64];
    const int nblk = NT * 256;
    const int cpx = nblk >> 3;
    const int bid = blockIdx.x;
    const int lin = (bid & 7) * cpx + (bid >> 3);
    const int mt = lin / NT, nt = lin - mt * NT;
    const int tid = threadIdx.x, wave = tid >> 6, lane = tid & 63;
    const int m0 = mt << 7, n0 = nt << 7;
    f32x4 acc[4][4] = {};

    for (int k0 = 0; k0 < K; k0 += 64) {
        __syncthreads();
        #pragma unroll
        for (int i = 0; i < 4; ++i) {
            int ins = wave * 4 + i;
            int r = ins * 8 + (lane >> 3);
            int c = (lane & 7) * 8;
            const unsigned short* sa = A + (size_t)(m0 + r) * K + k0 + c;
            const unsigned short* sb = W + (size_t)(n0 + r) * K + k0 + c;
            __builtin_amdgcn_global_load_lds(GCAST(sa), LCAST(As + ins * 512), 16, 0, 0);
            __builtin_amdgcn_global_load_lds(GCAST(sb), LCAST(Bs + ins * 512), 16, 0, 0);
        }
        __syncthreads();
        #pragma unroll
        for (int ks = 0; ks < 2; ++ks) {
            bf16x8 af[4], bfr[4];
            int kk = ks * 32 + ((lane >> 4) << 3);
            #pragma unroll
            for (int mi = 0; mi < 4; ++mi)
                af[mi] = *(const bf16x8*)(As + (((wave & 1) << 6) + mi * 16 + (lane & 15)) * 64 + kk);
            #pragma unroll
            for (int ni = 0; ni < 4; ++ni)
                bfr[ni] = *(const bf16x8*)(Bs + (((wave >> 1) << 6) + ni * 16 + (lane & 15)) * 64 + kk);
            #pragma unroll
            for (int mi = 0; mi < 4; ++mi)
                #pragma unroll
                for (int ni = 0; ni < 4; ++ni)
                    acc[mi][ni] = __builtin_amdgcn_mfma_f32_16x16x32_bf16(af[mi], bfr[ni], acc[mi][ni], 0, 0, 0);
        }
    }

    // epilogue: rows in this tile share one t; write scan-streaming layout
    const int tseq = m0 >> 9;
    const int d = n0 / 384;
    const int j0 = n0 - d * 384;
    const int bglob = (m0 & 511) + ((wave & 1) << 6) + ((lane >> 4) << 2);
    #pragma unroll
    for (int ni = 0; ni < 4; ++ni) {
        int j = j0 + ((wave >> 1) << 6) + ni * 16 + (lane & 15);
        float bias = cb[d * 384 + j];
        #pragma unroll
        for (int mi = 0; mi < 4; ++mi) {
            int b = bglob + mi * 16;
            int bs = b >> 4, bb = b & 15;
            ushort4 v;
            v.x = f2bf(acc[mi][ni][0] + bias);
            v.y = f2bf(acc[mi][ni][1] + bias);
            v.z = f2bf(acc[mi][ni][2] + bias);
            v.w = f2bf(acc[mi][ni][3] + bias);
            *(ushort4*)(gi + (((size_t)(d * 32 + bs) * 64 + tseq) * 384 + j) * 16 + bb) = v;
        }
    }
}

// ---------- GRU scan: 512 threads, 8 waves; wave w owns hidden cols [w*16,(w+1)*16) ----------
// 2-deep gi prefetch: issue->use distance = 2 MFMA phases + 2 barriers (~1300 cy) covers HBM latency.
__global__ __launch_bounds__(512, 1) void k_scan(
    const unsigned short* __restrict__ gi,   // [d][bs][t][j][bb]  (r,z parts pre-biased with bhh)
    const unsigned short* __restrict__ whh,  // [2][384][128] bf16
    const float* __restrict__ bhh,           // [2][384] (only n-gate part used)
    unsigned short* __restrict__ hout)       // [64][512][256]
{
    const int d = blockIdx.y, bs = blockIdx.x;
    const int b0 = bs << 4;
    const int tid = threadIdx.x, wave = tid >> 6, lane = tid & 63;
    __shared__ unsigned short hs[2][2048];   // 2 x (16 rows x 128 cols), XOR-swizzled
    for (int i = tid; i < 2048; i += 512) hs[0][i] = 0;

    const int colh = (wave << 4) + (lane & 15);
    // whh fragments: 3 gates x K=128 (4 slices)
    bf16x8 wf[3][4];
    #pragma unroll
    for (int g = 0; g < 3; ++g) {
        int j = g * 128 + colh;
        #pragma unroll
        for (int ks = 0; ks < 4; ++ks)
            wf[g][ks] = *(const bf16x8*)(whh + ((d * 384 + j) << 7) + ks * 32 + ((lane >> 4) << 3));
    }
    const float bh2 = bhh[d * 384 + 256 + colh];
    const float L2E = 1.4426950408889634f;

    int joff[3];
    #pragma unroll
    for (int g = 0; g < 3; ++g)
        joff[g] = (g * 128 + colh) * 16 + ((lane >> 4) << 2);

    // hoisted addressing: XOR mask applied AFTER the ks*64 add (mask bit6 overlaps ks*64!)
    const int arow = lane & 15;
    const int amask = (arow & 7) << 4;
    const int abase = (arow << 8) + (((lane >> 4) << 3) << 1);
    // gate LDS writes: rows r0..r0+3 at col colh (XOR-only, safe to hoist fully)
    const int r0 = (lane >> 4) << 2;
    const int c2 = colh << 1;
    const int wb0 = (((r0 + 0) << 8) + c2) ^ (((r0 + 0) & 7) << 4);
    const int wb1 = (((r0 + 1) << 8) + c2) ^ (((r0 + 1) & 7) << 4);
    const int wb2 = (((r0 + 2) << 8) + c2) ^ (((r0 + 2) & 7) << 4);
    const int wb3 = (((r0 + 3) << 8) + c2) ^ (((r0 + 3) & 7) << 4);

    // cooperative-store mapping: thread -> (srow, scol) of the 16x128 h tile
    const int srow = tid >> 5;
    const int scol = (tid & 31) << 2;
    const int sbyte = ((srow << 8) + (scol << 1)) ^ ((srow & 7) << 4);
    const int t0 = d ? 63 : 0;
    unsigned short* sp = hout + ((size_t)(t0 * 512 + b0 + srow)) * 256 + d * 128 + scol;
    const ptrdiff_t sdelta = d ? -(ptrdiff_t)131072 : (ptrdiff_t)131072;

    // streaming gi pointer, advanced by +-6144 elems per step
    const unsigned short* gp = gi + (size_t)(d * 32 + bs) * 64 * 6144 + (size_t)t0 * 6144;
    const ptrdiff_t gdelta = d ? -(ptrdiff_t)6144 : (ptrdiff_t)6144;

    float hold[4] = {};
    uint2 cur[3], nxt[3], nx2[3];
    #pragma unroll
    for (int g = 0; g < 3; ++g)
        cur[g] = *(const uint2*)(gp + joff[g]);
    gp += gdelta;
    #pragma unroll
    for (int g = 0; g < 3; ++g)
        nxt[g] = *(const uint2*)(gp + joff[g]);
    gp += gdelta;

    asm volatile("s_waitcnt lgkmcnt(0)" ::: "memory");
    __builtin_amdgcn_s_barrier();
    __builtin_amdgcn_sched_barrier(0);

    for (int s = 0; s < 64; ++s) {
        // prefetch gi for step s+2 (overreads near the end stay in-allocation, never consumed)
        #pragma unroll
        for (int g = 0; g < 3; ++g)
            nx2[g] = *(const uint2*)(gp + joff[g]);
        gp += gdelta;

        const unsigned short* hsrc = hs[s & 1];

        // cooperative store of h_{s-1} (lives in hsrc), overlapped with MFMA
        uint2 hv;
        if (s > 0) hv = *(const uint2*)((const char*)hsrc + sbyte);

        // gh = h @ whh.T for this wave's 16 cols x 3 gates
        f32x4 acc[3] = {};
        #pragma unroll
        for (int ks = 0; ks < 4; ++ks) {
            bf16x8 a = *(const bf16x8*)((const char*)hsrc + ((abase + ks * 64) ^ amask));
            #pragma unroll
            for (int g = 0; g < 3; ++g)
                acc[g] = __builtin_amdgcn_mfma_f32_16x16x32_bf16(a, wf[g][ks], acc[g], 0, 0, 0);
        }

        if (s > 0) { *(uint2*)sp = hv; sp += sdelta; }

        // gates: 4 batch rows (regs) x 1 col per thread; lean VALU forms
        unsigned short* hdst = hs[(s & 1) ^ 1];
        const ushort4 cr = *(const ushort4*)&cur[0];
        const ushort4 cz = *(const ushort4*)&cur[1];
        const ushort4 cn = *(const ushort4*)&cur[2];
        float hn[4];
        #pragma unroll
        for (int reg = 0; reg < 4; ++reg) {
            float r = rcp_raw(1.f + exp2_raw((bf2f((&cr.x)[reg]) + acc[0][reg]) * -L2E));
            float z = rcp_raw(1.f + exp2_raw((bf2f((&cz.x)[reg]) + acc[1][reg]) * -L2E));
            float gn = bf2f((&cn.x)[reg]) + r * (acc[2][reg] + bh2);
            float n = 1.f - 2.f * rcp_raw(1.f + exp2_raw(gn * (2.f * L2E)));
            hn[reg] = n + z * (hold[reg] - n);
            hold[reg] = hn[reg];
        }
        {
            unsigned p01 = cvt_pk_bf16(hn[0], hn[1]);
            unsigned p23 = cvt_pk_bf16(hn[2], hn[3]);
            *(unsigned short*)((char*)hdst + wb0) = (unsigned short)p01;
            *(unsigned short*)((char*)hdst + wb1) = (unsigned short)(p01 >> 16);
            *(unsigned short*)((char*)hdst + wb2) = (unsigned short)p23;
            *(unsigned short*)((char*)hdst + wb3) = (unsigned short)(p23 >> 16);
        }
        asm volatile("s_waitcnt lgkmcnt(0)" ::: "memory");
        __builtin_amdgcn_s_barrier();
        __builtin_amdgcn_sched_barrier(0);
        #pragma unroll
        for (int g = 0; g < 3; ++g) {
            cur[g] = nxt[g];
            nxt[g] = nx2[g];
        }
    }
    // final h_63 lives in hs[0]
    uint2 hv = *(const uint2*)((const char*)hs[0] + sbyte);
    *(uint2*)sp = hv;
}

// ---------- attention ----------
__global__ __launch_bounds__(256, 2) void k_attn(
    const unsigned short* __restrict__ h2,   // [64][512][256]
    const unsigned short* __restrict__ awT,  // [256][256] transposed att_w
    const float* __restrict__ att_b, const float* __restrict__ a_w, const float* __restrict__ a_b,
    float* __restrict__ out)                 // [512][256]
{
    const int b = blockIdx.x, tid = threadIdx.x, wave = tid >> 6, lane = tid & 63;
    __shared__ unsigned short vw[64 * 264];
    __shared__ float red[256];
    __shared__ float sc[64];
    __shared__ float scal[2];

    for (int i = tid; i < 2048; i += 256) {
        int t = i >> 5; int c = (i & 31) << 3;
        bf16x8 v = *(const bf16x8*)(h2 + ((size_t)t * 512 + b) * 256 + c);
        int byte = (t << 9) + (c << 1); byte ^= (t & 7) << 4;
        *(bf16x8*)((char*)vw + byte) = v;
    }
    __syncthreads();

    f32x4 acc[4][4] = {};
    const int colbase = wave << 6;
    #pragma unroll
    for (int ks = 0; ks < 8; ++ks) {
        bf16x8 a[4], bf[4];
        int kk = ks * 32 + ((lane >> 4) << 3);
        #pragma unroll
        for (int mt = 0; mt < 4; ++mt) {
            int row = mt * 16 + (lane & 15);
            int byte = (row << 9) + (kk << 1); byte ^= (row & 7) << 4;
            a[mt] = *(const bf16x8*)((const char*)vw + byte);
        }
        #pragma unroll
        for (int nt = 0; nt < 4; ++nt) {
            int cg = colbase + nt * 16 + (lane & 15);
            bf[nt] = *(const bf16x8*)(awT + cg * 256 + kk);
        }
        #pragma unroll
        for (int mt = 0; mt < 4; ++mt)
            #pragma unroll
            for (int nt = 0; nt < 4; ++nt)
                acc[mt][nt] = __builtin_amdgcn_mfma_f32_16x16x32_bf16(a[mt], bf[nt], acc[mt][nt], 0, 0, 0);
    }
    __syncthreads();

    #pragma unroll
    for (int mt = 0; mt < 4; ++mt)
        #pragma unroll
        for (int nt = 0; nt < 4; ++nt) {
            int cg = colbase + nt * 16 + (lane & 15);
            float bias = att_b[cg];
            int r0 = mt * 16 + ((lane >> 4) << 2);
            #pragma unroll
            for (int reg = 0; reg < 4; ++reg)
                vw[(r0 + reg) * 264 + cg] = f2bf(acc[mt][nt][reg] + bias);
        }
    __syncthreads();

    float wsum = 0.f;
    for (int t = 0; t < 64; ++t) wsum += bf2f(vw[t * 264 + tid]);
    float p = (wsum * (1.f / 64.f)) * a_w[tid];
    #pragma unroll
    for (int off = 32; off; off >>= 1) p += __shfl_down(p, off, 64);
    if (lane == 0) red[wave] = p;
    __syncthreads();
    float s0 = red[0] + red[1] + red[2] + red[3];
    __syncthreads();

    {
        int t4 = tid >> 2, part = tid & 3;
        float ps = 0.f;
        for (int c = part * 64; c < part * 64 + 64; ++c)
            ps += bf2f(vw[t4 * 264 + c]) * a_w[256 + c];
        red[tid] = ps;
    }
    __syncthreads();
    if (tid < 64) {
        float s = red[tid * 4] + red[tid * 4 + 1] + red[tid * 4 + 2] + red[tid * 4 + 3] + s0 + a_b[0];
        s = (s > 0.f) ? s : 0.01f * s;
        sc[tid] = __expf(s);
    }
    __syncthreads();
    if (tid < 64) {
        float e = sc[tid];
        #pragma unroll
        for (int off = 32; off; off >>= 1) e += __shfl_down(e, off, 64);
        if (tid == 0) scal[0] = e;
    }
    __syncthreads();
    const float inv_den = 1.f / scal[0];

    float o = 0.f;
    for (int t = 0; t < 64; ++t) o += sc[t] * bf2f(vw[t * 264 + tid]);
    out[b * 256 + tid] = fmaxf(o * inv_den, 0.f);
}

// ---------- launch ----------
extern "C" void kernel_launch(void* const* d_in, const int* in_sizes, int n_in,
                              void* d_out, int out_size, void* d_ws, size_t ws_size,
                              hipStream_t stream) {
    (void)in_sizes; (void)n_in; (void)out_size; (void)ws_size;
    const float* fa  = (const float*)d_in[0];
    const float* fb  = (const float*)d_in[1];
    const float* fl  = (const float*)d_in[2];
    const float* efi = (const float*)d_in[3];
    const int* esrc  = (const int*)d_in[4];
    const int* edst  = (const int*)d_in[5];

    char* ws = (char*)d_ws;
    unsigned short* tree = (unsigned short*)(ws);                    // 58,720,256 B
    unsigned short* h1   = (unsigned short*)(ws);                    // aliases tree (dead by then)
    unsigned short* h2   = (unsigned short*)(ws + 16777216);
    unsigned short* gi   = (unsigned short*)(ws + 58720256);         // 50,331,648 B
    unsigned short* X    = (unsigned short*)(ws + 58720256);         // aliases gi (dead before gemm0)
    unsigned short* wih0 = (unsigned short*)(ws + 109051904);
    unsigned short* wih1 = (unsigned short*)(ws + 110428160);
    unsigned short* whh0 = (unsigned short*)(ws + 110821376);
    unsigned short* whh1 = (unsigned short*)(ws + 111017984);
    unsigned short* awT  = (unsigned short*)(ws + 111214592);
    unsigned short* wcat = (unsigned short*)(ws + 111345664);        // 147,456 B
    float* cb0 = (float*)(ws + 111493120);                           // 3072 B
    float* cb1 = (float*)(ws + 111496192);                           // 3072 B

    k_prepw<<<4775, 256, 0, stream>>>(
        (const float*)d_in[14], (const float*)d_in[18], (const float*)d_in[15], (const float*)d_in[19],
        (const float*)d_in[22], (const float*)d_in[6], (const float*)d_in[8], (const float*)d_in[10],
        (const float*)d_in[16], (const float*)d_in[17], (const float*)d_in[20], (const float*)d_in[21],
        wih0, wih1, whh0, whh1, awT, wcat, cb0, cb1);

    k_pack<<<512, 256, 0, stream>>>(fa, fb, fl, X);
    k_nv<<<768, 256, 0, stream>>>(X, wcat,
        (const float*)d_in[7], (const float*)d_in[9], (const float*)d_in[11], tree);
    k_agg<<<512, 256, 0, stream>>>(tree, efi, esrc, edst,
        (const float*)d_in[12], (const float*)d_in[13]);

    k_gemm<6><<<1536, 256, 0, stream>>>(tree, wih0, cb0, gi, 896);
    k_scan<<<dim3(32, 2), 512, 0, stream>>>(gi, whh0, (const float*)d_in[17], h1);
    k_gemm<6><<<1536, 256, 0, stream>>>(h1, wih1, cb1, gi, 256);
    k_scan<<<dim3(32, 2), 512, 0, stream>>>(gi, whh1, (const float*)d_in[21], h2);
    k_attn<<<512, 256, 0, stream>>>(h2, awT, (const float*)d_in[23], (const float*)d_in[24],
                                    (const float*)d_in[25], (float*)d_out);
}